// Round 7
// baseline (9639.242 us; speedup 1.0000x reference)
//
#include <hip/hip_runtime.h>

// ---------------------------------------------------------------------------
// NodeNetwork: agg(sum over deg=16) -> concat(3x128) -> MLP(384-256-256-128)
//              -> row L2 normalize.  N=500000 rows.
// R7: MEASUREMENT ROUND. node_net = the R2/R3 562us structure, repeated 6x
// in-kernel (runtime `reps` arg, idempotent) so its dispatch (~3.4ms) beats
// the 2.65ms harness ws-poison fills into rocprof's top-5, exposing
// MfmaUtil / VALUBusy / Occupancy / LDS_BANK_CONFLICT for the first time.
// agg_kernel / prep_weights unchanged (agg is at the read roofline per R5).
// ---------------------------------------------------------------------------

typedef short short8   __attribute__((ext_vector_type(8)));
typedef short short4_t __attribute__((ext_vector_type(4)));
typedef float f32x4    __attribute__((ext_vector_type(4)));

#define SWZ(row, off) ((off) ^ (((row) & 7) << 4))

__device__ __forceinline__ unsigned short f2bf(float f) {
    unsigned int u = __float_as_uint(f);
    u += 0x7fffu + ((u >> 16) & 1u);   // round-to-nearest-even
    return (unsigned short)(u >> 16);
}

// ---------------------------------------------------------------------------
// Weight prep (unchanged): fp32->bf16, per-lane MFMA B-fragment order.
// ---------------------------------------------------------------------------
__global__ void prep_weights(const float* __restrict__ W1,
                             const float* __restrict__ W2,
                             const float* __restrict__ W3,
                             short* __restrict__ pw1,
                             short* __restrict__ pw2,
                             short* __restrict__ pw3) {
    int idx = blockIdx.x * 256 + threadIdx.x;
    if (idx < 98304) {                       // W1 [384][256]
        int j = idx & 7, l = (idx >> 3) & 63, g = idx >> 9;
        int ks = g % 12, tn = g / 12;
        int n = tn * 16 + (l & 15);
        int k = ks * 32 + ((l >> 4) << 3) + j;
        pw1[idx] = (short)f2bf(W1[k * 256 + n]);
    } else if (idx < 98304 + 65536) {        // W2 [256][256]
        int e = idx - 98304;
        int j = e & 7, l = (e >> 3) & 63, g = e >> 9;
        int ks = g & 7, tn = g >> 3;
        int n = tn * 16 + (l & 15);
        int k = ks * 32 + ((l >> 4) << 3) + j;
        pw2[e] = (short)f2bf(W2[k * 256 + n]);
    } else if (idx < 98304 + 65536 + 32768) { // W3 [256][128]
        int e = idx - 98304 - 65536;
        int j = e & 7, l = (e >> 3) & 63, g = e >> 9;
        int ks = g & 7, tn = g >> 3;
        int n = tn * 16 + (l & 15);
        int k = ks * 32 + ((l >> 4) << 3) + j;
        pw3[e] = (short)f2bf(W3[k * 128 + n]);
    }
}

// ---------------------------------------------------------------------------
// Kernel A (unchanged, ~read roofline): streaming deg-16 reduction.
// ---------------------------------------------------------------------------
__global__ __launch_bounds__(256) void agg_kernel(
    const float* __restrict__ msg, short* __restrict__ agg, int n_rows)
{
    const int w = threadIdx.x >> 6;
    const int l = threadIdx.x & 63;
    const long long pb = (long long)blockIdx.x * 8 + 2 * w;  // pair base row
    if (pb >= n_rows) return;

    const f32x4* base = (const f32x4*)((const char*)msg + pb * 8192);
    f32x4 tA[8], tB[8];
    const bool okB = (pb + 1) < n_rows;
    #pragma unroll
    for (int i = 0; i < 8; ++i) tA[i] = __builtin_nontemporal_load(base + i * 64 + l);
    if (okB) {
        #pragma unroll
        for (int i = 0; i < 8; ++i) tB[i] = __builtin_nontemporal_load(base + (8 + i) * 64 + l);
    } else {
        #pragma unroll
        for (int i = 0; i < 8; ++i) tB[i] = (f32x4){0.f, 0.f, 0.f, 0.f};
    }
    f32x4 sA = ((tA[0] + tA[1]) + (tA[2] + tA[3])) + ((tA[4] + tA[5]) + (tA[6] + tA[7]));
    f32x4 sB = ((tB[0] + tB[1]) + (tB[2] + tB[3])) + ((tB[4] + tB[5]) + (tB[6] + tB[7]));
    #pragma unroll
    for (int c = 0; c < 4; ++c) {
        sA[c] += __shfl_xor(sA[c], 32);
        sB[c] += __shfl_xor(sB[c], 32);
    }
    f32x4 s = (l < 32) ? sA : sB;
    short4_t s4;
    s4[0] = (short)f2bf(s[0]); s4[1] = (short)f2bf(s[1]);
    s4[2] = (short)f2bf(s[2]); s4[3] = (short)f2bf(s[3]);
    const long long orow = pb + (l >> 5);
    if (orow < n_rows)
        *(short4_t*)(agg + orow * 128 + (l & 31) * 4) = s4;
}

// ---------------------------------------------------------------------------
// Kernel B: the R2-structure MLP (562us @ reps=1), body repeated `reps`
// times. asm memory clobber per rep prevents cross-rep load hoisting.
// Rep seam is race-free: norm reads regA pre-sync1(next rep); the only
// pre-sync1 writes of the next rep touch regB's agg region, whose prior
// readers (GEMM3) are fenced by sync6.
// ---------------------------------------------------------------------------
__global__ __launch_bounds__(256, 4) void node_net(
    const short* __restrict__ aggb,
    const float* __restrict__ feat,
    const float* __restrict__ glob,
    const float* __restrict__ b1v,
    const float* __restrict__ b2v,
    const float* __restrict__ b3v,
    const short* __restrict__ pw1,
    const short* __restrict__ pw2,
    const short* __restrict__ pw3,
    float* __restrict__ out,
    int n_rows, int reps)
{
    __shared__ char lds[32768];
    char* regA = lds;            // 16KB
    char* regB = lds + 16384;    // 16KB

    const int tid  = threadIdx.x;
    const int lane = tid & 63;
    const int w    = tid >> 6;
    const int lr   = lane & 15;
    const int lk   = lane >> 4;
    const long long r0 = (long long)blockIdx.x * 32;

    const f32x4 zero4 = {0.f, 0.f, 0.f, 0.f};

    for (int rep = 0; rep < reps; ++rep) {
        asm volatile("" ::: "memory");   // force real reloads each rep

        // ---- issue ALL global loads now: feat/glob into regs ----
        f32x4 fr[4], gr[4];
        #pragma unroll
        for (int q = 0; q < 4; ++q) {
            int r = (tid >> 5) + q * 8;
            long long row = r0 + r;
            fr[q] = zero4; gr[q] = zero4;
            if (row < n_rows) {
                fr[q] = ((const f32x4*)feat)[row * 32 + (tid & 31)];
                gr[q] = ((const f32x4*)glob)[row * 32 + (tid & 31)];
            }
        }

        // ---- stage agg (bf16) -> regB[0:8K] ----
        #pragma unroll
        for (int pass = 0; pass < 2; ++pass) {
            int r = tid >> 3;
            int c = (tid & 7) + 8 * pass;
            long long row = r0 + r;
            short8 v = {0, 0, 0, 0, 0, 0, 0, 0};
            if (row < n_rows) v = *(const short8*)(aggb + row * 128 + c * 8);
            *(short8*)(regB + SWZ(r, r * 256 + c * 16)) = v;
        }
        __syncthreads();                                   // sync1

        // ---- stage feat regs -> regA[0:8K] (consumed after sync2) ----
        #pragma unroll
        for (int q = 0; q < 4; ++q) {
            int r = (tid >> 5) + q * 8;
            short4_t s4;
            s4[0] = (short)f2bf(fr[q][0]); s4[1] = (short)f2bf(fr[q][1]);
            s4[2] = (short)f2bf(fr[q][2]); s4[3] = (short)f2bf(fr[q][3]);
            *(short4_t*)(regA + SWZ(r, r * 256 + (tid & 31) * 8)) = s4;
        }

        f32x4 acc1[2][4];
        #pragma unroll
        for (int ri = 0; ri < 2; ++ri)
            #pragma unroll
            for (int ci = 0; ci < 4; ++ci) acc1[ri][ci] = zero4;

        // ---- GEMM1 part 0 (agg), ks = 0..3, reads regB[0:8K] ----
        #pragma unroll
        for (int s = 0; s < 4; ++s) {
            short8 a[2], b[4];
            #pragma unroll
            for (int ri = 0; ri < 2; ++ri) {
                int row = ri * 16 + lr;
                a[ri] = *(const short8*)(regB + SWZ(row, row * 256 + s * 64 + lk * 16));
            }
            #pragma unroll
            for (int ci = 0; ci < 4; ++ci) {
                int tn = w * 4 + ci;
                b[ci] = *(const short8*)(pw1 + (((tn * 12 + s) * 64 + lane) << 3));
            }
            #pragma unroll
            for (int ri = 0; ri < 2; ++ri)
                #pragma unroll
                for (int ci = 0; ci < 4; ++ci)
                    acc1[ri][ci] = __builtin_amdgcn_mfma_f32_16x16x32_bf16(
                        a[ri], b[ci], acc1[ri][ci], 0, 0, 0);
        }
        __syncthreads();                                   // sync2

        // ---- stage glob regs -> regB[8K:16K] (consumed after sync3) ----
        #pragma unroll
        for (int q = 0; q < 4; ++q) {
            int r = (tid >> 5) + q * 8;
            short4_t s4;
            s4[0] = (short)f2bf(gr[q][0]); s4[1] = (short)f2bf(gr[q][1]);
            s4[2] = (short)f2bf(gr[q][2]); s4[3] = (short)f2bf(gr[q][3]);
            *(short4_t*)(regB + 8192 + SWZ(r, r * 256 + (tid & 31) * 8)) = s4;
        }

        // ---- GEMM1 part 1 (feat), ks = 4..7, reads regA[0:8K] ----
        #pragma unroll
        for (int s = 0; s < 4; ++s) {
            short8 a[2], b[4];
            #pragma unroll
            for (int ri = 0; ri < 2; ++ri) {
                int row = ri * 16 + lr;
                a[ri] = *(const short8*)(regA + SWZ(row, row * 256 + s * 64 + lk * 16));
            }
            #pragma unroll
            for (int ci = 0; ci < 4; ++ci) {
                int tn = w * 4 + ci;
                b[ci] = *(const short8*)(pw1 + (((tn * 12 + 4 + s) * 64 + lane) << 3));
            }
            #pragma unroll
            for (int ri = 0; ri < 2; ++ri)
                #pragma unroll
                for (int ci = 0; ci < 4; ++ci)
                    acc1[ri][ci] = __builtin_amdgcn_mfma_f32_16x16x32_bf16(
                        a[ri], b[ci], acc1[ri][ci], 0, 0, 0);
        }
        __syncthreads();                                   // sync3

        // ---- GEMM1 part 2 (glob), ks = 8..11, reads regB[8K:16K] ----
        #pragma unroll
        for (int s = 0; s < 4; ++s) {
            short8 a[2], b[4];
            #pragma unroll
            for (int ri = 0; ri < 2; ++ri) {
                int row = ri * 16 + lr;
                a[ri] = *(const short8*)(regB + 8192 + SWZ(row, row * 256 + s * 64 + lk * 16));
            }
            #pragma unroll
            for (int ci = 0; ci < 4; ++ci) {
                int tn = w * 4 + ci;
                b[ci] = *(const short8*)(pw1 + (((tn * 12 + 8 + s) * 64 + lane) << 3));
            }
            #pragma unroll
            for (int ri = 0; ri < 2; ++ri)
                #pragma unroll
                for (int ci = 0; ci < 4; ++ci)
                    acc1[ri][ci] = __builtin_amdgcn_mfma_f32_16x16x32_bf16(
                        a[ri], b[ci], acc1[ri][ci], 0, 0, 0);
        }

        // ---- epilogue 1: +b1, ReLU, bf16 -> h1 in regA ----
        #pragma unroll
        for (int ci = 0; ci < 4; ++ci) {
            int col = w * 64 + ci * 16 + lr;
            float bias = b1v[col];
            #pragma unroll
            for (int ri = 0; ri < 2; ++ri)
                #pragma unroll
                for (int i = 0; i < 4; ++i) {
                    int row = ri * 16 + lk * 4 + i;
                    float v = fmaxf(acc1[ri][ci][i] + bias, 0.f);
                    *(short*)(regA + SWZ(row, row * 512 + col * 2)) = (short)f2bf(v);
                }
        }
        __syncthreads();                                   // sync4

        // ---- GEMM2: h1 @ W2 (reads regA) ----
        f32x4 acc2[2][4];
        #pragma unroll
        for (int ri = 0; ri < 2; ++ri)
            #pragma unroll
            for (int ci = 0; ci < 4; ++ci) acc2[ri][ci] = zero4;

        #pragma unroll
        for (int s = 0; s < 8; ++s) {
            short8 a[2], b[4];
            #pragma unroll
            for (int ri = 0; ri < 2; ++ri) {
                int row = ri * 16 + lr;
                a[ri] = *(const short8*)(regA + SWZ(row, row * 512 + s * 64 + lk * 16));
            }
            #pragma unroll
            for (int ci = 0; ci < 4; ++ci) {
                int tn = w * 4 + ci;
                b[ci] = *(const short8*)(pw2 + (((tn * 8 + s) * 64 + lane) << 3));
            }
            #pragma unroll
            for (int ri = 0; ri < 2; ++ri)
                #pragma unroll
                for (int ci = 0; ci < 4; ++ci)
                    acc2[ri][ci] = __builtin_amdgcn_mfma_f32_16x16x32_bf16(
                        a[ri], b[ci], acc2[ri][ci], 0, 0, 0);
        }

        // ---- epilogue 2: +b2, ReLU, bf16 -> h2 in regB ----
        #pragma unroll
        for (int ci = 0; ci < 4; ++ci) {
            int col = w * 64 + ci * 16 + lr;
            float bias = b2v[col];
            #pragma unroll
            for (int ri = 0; ri < 2; ++ri)
                #pragma unroll
                for (int i = 0; i < 4; ++i) {
                    int row = ri * 16 + lk * 4 + i;
                    float v = fmaxf(acc2[ri][ci][i] + bias, 0.f);
                    *(short*)(regB + SWZ(row, row * 512 + col * 2)) = (short)f2bf(v);
                }
        }
        __syncthreads();                                   // sync5

        // ---- GEMM3: h2 @ W3 (reads regB) ----
        f32x4 acc3[2][2];
        #pragma unroll
        for (int ri = 0; ri < 2; ++ri)
            #pragma unroll
            for (int ci = 0; ci < 2; ++ci) acc3[ri][ci] = zero4;

        #pragma unroll
        for (int s = 0; s < 8; ++s) {
            short8 a[2], b[2];
            #pragma unroll
            for (int ri = 0; ri < 2; ++ri) {
                int row = ri * 16 + lr;
                a[ri] = *(const short8*)(regB + SWZ(row, row * 512 + s * 64 + lk * 16));
            }
            #pragma unroll
            for (int ci = 0; ci < 2; ++ci) {
                int tn = w * 2 + ci;
                b[ci] = *(const short8*)(pw3 + (((tn * 8 + s) * 64 + lane) << 3));
            }
            #pragma unroll
            for (int ri = 0; ri < 2; ++ri)
                #pragma unroll
                for (int ci = 0; ci < 2; ++ci)
                    acc3[ri][ci] = __builtin_amdgcn_mfma_f32_16x16x32_bf16(
                        a[ri], b[ci], acc3[ri][ci], 0, 0, 0);
        }

        // ---- epilogue 3: +b3, f32 -> out tile in regA ----
        #pragma unroll
        for (int ci = 0; ci < 2; ++ci) {
            int col = w * 32 + ci * 16 + lr;
            float bias = b3v[col];
            #pragma unroll
            for (int ri = 0; ri < 2; ++ri)
                #pragma unroll
                for (int i = 0; i < 4; ++i) {
                    int row = ri * 16 + lk * 4 + i;
                    float v = acc3[ri][ci][i] + bias;
                    *(float*)(regA + SWZ(row, row * 512 + col * 4)) = v;
                }
        }
        __syncthreads();                                   // sync6

        // ---- row-wise L2 normalize + coalesced store ----
        #pragma unroll
        for (int pass = 0; pass < 4; ++pass) {
            const int r  = (tid >> 5) + pass * 8;
            const int fl = tid & 31;
            f32x4 v = *(const f32x4*)(regA + SWZ(r, r * 512 + fl * 16));
            float ss = v[0]*v[0] + v[1]*v[1] + v[2]*v[2] + v[3]*v[3];
            ss += __shfl_xor(ss, 1, 32);
            ss += __shfl_xor(ss, 2, 32);
            ss += __shfl_xor(ss, 4, 32);
            ss += __shfl_xor(ss, 8, 32);
            ss += __shfl_xor(ss, 16, 32);
            float inv = 1.f / (sqrtf(ss) + 1e-8f);
            long long row = r0 + r;
            if (row < n_rows) {
                f32x4 o = v * inv;
                ((f32x4*)out)[row * 32 + fl] = o;
            }
        }
    }
}

// ---------------------------------------------------------------------------
extern "C" void kernel_launch(void* const* d_in, const int* in_sizes, int n_in,
                              void* d_out, int out_size, void* d_ws, size_t ws_size,
                              hipStream_t stream) {
    const float* msg  = (const float*)d_in[0];
    const float* feat = (const float*)d_in[1];
    const float* glob = (const float*)d_in[2];
    const float* W1   = (const float*)d_in[3];
    const float* b1   = (const float*)d_in[4];
    const float* W2   = (const float*)d_in[5];
    const float* b2   = (const float*)d_in[6];
    const float* W3   = (const float*)d_in[7];
    const float* b3   = (const float*)d_in[8];
    float* out = (float*)d_out;

    const int n_rows = in_sizes[1] / 128;   // features is [N,128]

    short* pw1  = (short*)d_ws;             // 98304 bf16
    short* pw2  = pw1 + 98304;              // 65536 bf16
    short* pw3  = pw2 + 65536;              // 32768 bf16
    short* aggb = pw3 + 32768;              // N*128 bf16 (128 MB @ N=500k)

    hipLaunchKernelGGL(prep_weights, dim3(768), dim3(256), 0, stream,
                       W1, W2, W3, pw1, pw2, pw3);

    const int ablocks = (n_rows + 7) / 8;   // 8 rows per block
    hipLaunchKernelGGL(agg_kernel, dim3(ablocks), dim3(256), 0, stream,
                       msg, aggb, n_rows);

    const int nblocks = (n_rows + 31) / 32;
    // reps=6: single ~3.4ms dispatch > 2.65ms poison fills -> rocprof top-1.
    hipLaunchKernelGGL(node_net, dim3(nblocks), dim3(256), 0, stream,
                       aggb, feat, glob, b1, b2, b3, pw1, pw2, pw3, out,
                       n_rows, 6);
}

// Round 8
// 1157.438 us; speedup vs baseline: 8.3281x; 8.3281x over previous
//
#include <hip/hip_runtime.h>

// ---------------------------------------------------------------------------
// NodeNetwork: agg(sum over deg=16) -> concat(3x128) -> MLP(384-256-256-128)
//              -> row L2 normalize.  N=500000 rows.
// R8: R7's counters showed node_net is HBM-bound on EVICTED WEIGHT traffic
// (FETCH 2.45GB/rep vs 0.64GB inputs; MfmaUtil/VALUBusy ~5%): the input
// streams flush L2, so per-block weight fragment loads (6GB/rep aggregate)
// partially miss to HBM. Fix: nontemporal (no-L2-allocate) hints on ALL
// node_net streams (aggb/feat/glob loads, out stores) so weights stay
// L2-resident. Structure otherwise byte-identical to the 562us R2 kernel.
// agg_kernel / prep_weights unchanged.
// ---------------------------------------------------------------------------

typedef short short8   __attribute__((ext_vector_type(8)));
typedef short short4_t __attribute__((ext_vector_type(4)));
typedef float f32x4    __attribute__((ext_vector_type(4)));

#define SWZ(row, off) ((off) ^ (((row) & 7) << 4))

__device__ __forceinline__ unsigned short f2bf(float f) {
    unsigned int u = __float_as_uint(f);
    u += 0x7fffu + ((u >> 16) & 1u);   // round-to-nearest-even
    return (unsigned short)(u >> 16);
}

// ---------------------------------------------------------------------------
// Weight prep (unchanged): fp32->bf16, per-lane MFMA B-fragment order:
//   pw[((tn*KS + ks)*64 + lane)*8 + j] = bf16( W[k][n] )
//   n = tn*16 + (lane&15), k = ks*32 + (lane>>4)*8 + j
// ---------------------------------------------------------------------------
__global__ void prep_weights(const float* __restrict__ W1,
                             const float* __restrict__ W2,
                             const float* __restrict__ W3,
                             short* __restrict__ pw1,
                             short* __restrict__ pw2,
                             short* __restrict__ pw3) {
    int idx = blockIdx.x * 256 + threadIdx.x;
    if (idx < 98304) {                       // W1 [384][256]
        int j = idx & 7, l = (idx >> 3) & 63, g = idx >> 9;
        int ks = g % 12, tn = g / 12;
        int n = tn * 16 + (l & 15);
        int k = ks * 32 + ((l >> 4) << 3) + j;
        pw1[idx] = (short)f2bf(W1[k * 256 + n]);
    } else if (idx < 98304 + 65536) {        // W2 [256][256]
        int e = idx - 98304;
        int j = e & 7, l = (e >> 3) & 63, g = e >> 9;
        int ks = g & 7, tn = g >> 3;
        int n = tn * 16 + (l & 15);
        int k = ks * 32 + ((l >> 4) << 3) + j;
        pw2[e] = (short)f2bf(W2[k * 256 + n]);
    } else if (idx < 98304 + 65536 + 32768) { // W3 [256][128]
        int e = idx - 98304 - 65536;
        int j = e & 7, l = (e >> 3) & 63, g = e >> 9;
        int ks = g & 7, tn = g >> 3;
        int n = tn * 16 + (l & 15);
        int k = ks * 32 + ((l >> 4) << 3) + j;
        pw3[e] = (short)f2bf(W3[k * 128 + n]);
    }
}

// ---------------------------------------------------------------------------
// Kernel A (unchanged, ~read roofline): streaming deg-16 reduction, 1KB
// wave-contiguous nontemporal loads, shfl-merge, 512B contiguous bf16 store.
// ---------------------------------------------------------------------------
__global__ __launch_bounds__(256) void agg_kernel(
    const float* __restrict__ msg, short* __restrict__ agg, int n_rows)
{
    const int w = threadIdx.x >> 6;
    const int l = threadIdx.x & 63;
    const long long pb = (long long)blockIdx.x * 8 + 2 * w;  // pair base row
    if (pb >= n_rows) return;

    const f32x4* base = (const f32x4*)((const char*)msg + pb * 8192);
    f32x4 tA[8], tB[8];
    const bool okB = (pb + 1) < n_rows;
    #pragma unroll
    for (int i = 0; i < 8; ++i) tA[i] = __builtin_nontemporal_load(base + i * 64 + l);
    if (okB) {
        #pragma unroll
        for (int i = 0; i < 8; ++i) tB[i] = __builtin_nontemporal_load(base + (8 + i) * 64 + l);
    } else {
        #pragma unroll
        for (int i = 0; i < 8; ++i) tB[i] = (f32x4){0.f, 0.f, 0.f, 0.f};
    }
    f32x4 sA = ((tA[0] + tA[1]) + (tA[2] + tA[3])) + ((tA[4] + tA[5]) + (tA[6] + tA[7]));
    f32x4 sB = ((tB[0] + tB[1]) + (tB[2] + tB[3])) + ((tB[4] + tB[5]) + (tB[6] + tB[7]));
    #pragma unroll
    for (int c = 0; c < 4; ++c) {
        sA[c] += __shfl_xor(sA[c], 32);
        sB[c] += __shfl_xor(sB[c], 32);
    }
    f32x4 s = (l < 32) ? sA : sB;
    short4_t s4;
    s4[0] = (short)f2bf(s[0]); s4[1] = (short)f2bf(s[1]);
    s4[2] = (short)f2bf(s[2]); s4[3] = (short)f2bf(s[3]);
    const long long orow = pb + (l >> 5);
    if (orow < n_rows)
        *(short4_t*)(agg + orow * 128 + (l & 31) * 4) = s4;
}

// ---------------------------------------------------------------------------
// Kernel B: MLP — R2 structure, 32 rows/block, 256 threads, 32KB LDS.
// ONLY change vs R2: nontemporal loads (aggb/feat/glob) + nontemporal
// stores (out) so the streams bypass L2 allocation and weights stay hot.
// ---------------------------------------------------------------------------
__global__ __launch_bounds__(256, 4) void node_net(
    const short* __restrict__ aggb,
    const float* __restrict__ feat,
    const float* __restrict__ glob,
    const float* __restrict__ b1v,
    const float* __restrict__ b2v,
    const float* __restrict__ b3v,
    const short* __restrict__ pw1,
    const short* __restrict__ pw2,
    const short* __restrict__ pw3,
    float* __restrict__ out,
    int n_rows)
{
    __shared__ char lds[32768];
    char* regA = lds;            // 16KB
    char* regB = lds + 16384;    // 16KB

    const int tid  = threadIdx.x;
    const int lane = tid & 63;
    const int w    = tid >> 6;
    const int lr   = lane & 15;
    const int lk   = lane >> 4;
    const long long r0 = (long long)blockIdx.x * 32;

    const f32x4 zero4 = {0.f, 0.f, 0.f, 0.f};

    // ---- issue ALL global loads now: feat/glob into regs (NT: no L2 alloc) ----
    f32x4 fr[4], gr[4];
    #pragma unroll
    for (int q = 0; q < 4; ++q) {
        int r = (tid >> 5) + q * 8;
        long long row = r0 + r;
        fr[q] = zero4; gr[q] = zero4;
        if (row < n_rows) {
            fr[q] = __builtin_nontemporal_load((const f32x4*)feat + row * 32 + (tid & 31));
            gr[q] = __builtin_nontemporal_load((const f32x4*)glob + row * 32 + (tid & 31));
        }
    }

    // ---- stage agg (bf16, NT) -> regB[0:8K] ----
    #pragma unroll
    for (int pass = 0; pass < 2; ++pass) {
        int r = tid >> 3;
        int c = (tid & 7) + 8 * pass;
        long long row = r0 + r;
        short8 v = {0, 0, 0, 0, 0, 0, 0, 0};
        if (row < n_rows) v = __builtin_nontemporal_load((const short8*)(aggb + row * 128 + c * 8));
        *(short8*)(regB + SWZ(r, r * 256 + c * 16)) = v;
    }
    __syncthreads();                                   // sync1

    // ---- stage feat regs -> regA[0:8K] (consumed after sync2) ----
    #pragma unroll
    for (int q = 0; q < 4; ++q) {
        int r = (tid >> 5) + q * 8;
        short4_t s4;
        s4[0] = (short)f2bf(fr[q][0]); s4[1] = (short)f2bf(fr[q][1]);
        s4[2] = (short)f2bf(fr[q][2]); s4[3] = (short)f2bf(fr[q][3]);
        *(short4_t*)(regA + SWZ(r, r * 256 + (tid & 31) * 8)) = s4;
    }

    f32x4 acc1[2][4];
    #pragma unroll
    for (int ri = 0; ri < 2; ++ri)
        #pragma unroll
        for (int ci = 0; ci < 4; ++ci) acc1[ri][ci] = zero4;

    // ---- GEMM1 part 0 (agg), ks = 0..3, reads regB[0:8K] ----
    #pragma unroll
    for (int s = 0; s < 4; ++s) {
        short8 a[2], b[4];
        #pragma unroll
        for (int ri = 0; ri < 2; ++ri) {
            int row = ri * 16 + lr;
            a[ri] = *(const short8*)(regB + SWZ(row, row * 256 + s * 64 + lk * 16));
        }
        #pragma unroll
        for (int ci = 0; ci < 4; ++ci) {
            int tn = w * 4 + ci;
            b[ci] = *(const short8*)(pw1 + (((tn * 12 + s) * 64 + lane) << 3));
        }
        #pragma unroll
        for (int ri = 0; ri < 2; ++ri)
            #pragma unroll
            for (int ci = 0; ci < 4; ++ci)
                acc1[ri][ci] = __builtin_amdgcn_mfma_f32_16x16x32_bf16(
                    a[ri], b[ci], acc1[ri][ci], 0, 0, 0);
    }
    __syncthreads();                                   // sync2

    // ---- stage glob regs -> regB[8K:16K] (consumed after sync3) ----
    #pragma unroll
    for (int q = 0; q < 4; ++q) {
        int r = (tid >> 5) + q * 8;
        short4_t s4;
        s4[0] = (short)f2bf(gr[q][0]); s4[1] = (short)f2bf(gr[q][1]);
        s4[2] = (short)f2bf(gr[q][2]); s4[3] = (short)f2bf(gr[q][3]);
        *(short4_t*)(regB + 8192 + SWZ(r, r * 256 + (tid & 31) * 8)) = s4;
    }

    // ---- GEMM1 part 1 (feat), ks = 4..7, reads regA[0:8K] ----
    #pragma unroll
    for (int s = 0; s < 4; ++s) {
        short8 a[2], b[4];
        #pragma unroll
        for (int ri = 0; ri < 2; ++ri) {
            int row = ri * 16 + lr;
            a[ri] = *(const short8*)(regA + SWZ(row, row * 256 + s * 64 + lk * 16));
        }
        #pragma unroll
        for (int ci = 0; ci < 4; ++ci) {
            int tn = w * 4 + ci;
            b[ci] = *(const short8*)(pw1 + (((tn * 12 + 4 + s) * 64 + lane) << 3));
        }
        #pragma unroll
        for (int ri = 0; ri < 2; ++ri)
            #pragma unroll
            for (int ci = 0; ci < 4; ++ci)
                acc1[ri][ci] = __builtin_amdgcn_mfma_f32_16x16x32_bf16(
                    a[ri], b[ci], acc1[ri][ci], 0, 0, 0);
    }
    __syncthreads();                                   // sync3

    // ---- GEMM1 part 2 (glob), ks = 8..11, reads regB[8K:16K] ----
    #pragma unroll
    for (int s = 0; s < 4; ++s) {
        short8 a[2], b[4];
        #pragma unroll
        for (int ri = 0; ri < 2; ++ri) {
            int row = ri * 16 + lr;
            a[ri] = *(const short8*)(regB + 8192 + SWZ(row, row * 256 + s * 64 + lk * 16));
        }
        #pragma unroll
        for (int ci = 0; ci < 4; ++ci) {
            int tn = w * 4 + ci;
            b[ci] = *(const short8*)(pw1 + (((tn * 12 + 8 + s) * 64 + lane) << 3));
        }
        #pragma unroll
        for (int ri = 0; ri < 2; ++ri)
            #pragma unroll
            for (int ci = 0; ci < 4; ++ci)
                acc1[ri][ci] = __builtin_amdgcn_mfma_f32_16x16x32_bf16(
                    a[ri], b[ci], acc1[ri][ci], 0, 0, 0);
    }

    // ---- epilogue 1: +b1, ReLU, bf16 -> h1 in regA ----
    #pragma unroll
    for (int ci = 0; ci < 4; ++ci) {
        int col = w * 64 + ci * 16 + lr;
        float bias = b1v[col];
        #pragma unroll
        for (int ri = 0; ri < 2; ++ri)
            #pragma unroll
            for (int i = 0; i < 4; ++i) {
                int row = ri * 16 + lk * 4 + i;
                float v = fmaxf(acc1[ri][ci][i] + bias, 0.f);
                *(short*)(regA + SWZ(row, row * 512 + col * 2)) = (short)f2bf(v);
            }
    }
    __syncthreads();                                   // sync4

    // ---- GEMM2: h1 @ W2 (reads regA) ----
    f32x4 acc2[2][4];
    #pragma unroll
    for (int ri = 0; ri < 2; ++ri)
        #pragma unroll
        for (int ci = 0; ci < 4; ++ci) acc2[ri][ci] = zero4;

    #pragma unroll
    for (int s = 0; s < 8; ++s) {
        short8 a[2], b[4];
        #pragma unroll
        for (int ri = 0; ri < 2; ++ri) {
            int row = ri * 16 + lr;
            a[ri] = *(const short8*)(regA + SWZ(row, row * 512 + s * 64 + lk * 16));
        }
        #pragma unroll
        for (int ci = 0; ci < 4; ++ci) {
            int tn = w * 4 + ci;
            b[ci] = *(const short8*)(pw2 + (((tn * 8 + s) * 64 + lane) << 3));
        }
        #pragma unroll
        for (int ri = 0; ri < 2; ++ri)
            #pragma unroll
            for (int ci = 0; ci < 4; ++ci)
                acc2[ri][ci] = __builtin_amdgcn_mfma_f32_16x16x32_bf16(
                    a[ri], b[ci], acc2[ri][ci], 0, 0, 0);
    }

    // ---- epilogue 2: +b2, ReLU, bf16 -> h2 in regB ----
    #pragma unroll
    for (int ci = 0; ci < 4; ++ci) {
        int col = w * 64 + ci * 16 + lr;
        float bias = b2v[col];
        #pragma unroll
        for (int ri = 0; ri < 2; ++ri)
            #pragma unroll
            for (int i = 0; i < 4; ++i) {
                int row = ri * 16 + lk * 4 + i;
                float v = fmaxf(acc2[ri][ci][i] + bias, 0.f);
                *(short*)(regB + SWZ(row, row * 512 + col * 2)) = (short)f2bf(v);
            }
    }
    __syncthreads();                                   // sync5

    // ---- GEMM3: h2 @ W3 (reads regB) ----
    f32x4 acc3[2][2];
    #pragma unroll
    for (int ri = 0; ri < 2; ++ri)
        #pragma unroll
        for (int ci = 0; ci < 2; ++ci) acc3[ri][ci] = zero4;

    #pragma unroll
    for (int s = 0; s < 8; ++s) {
        short8 a[2], b[2];
        #pragma unroll
        for (int ri = 0; ri < 2; ++ri) {
            int row = ri * 16 + lr;
            a[ri] = *(const short8*)(regB + SWZ(row, row * 512 + s * 64 + lk * 16));
        }
        #pragma unroll
        for (int ci = 0; ci < 2; ++ci) {
            int tn = w * 2 + ci;
            b[ci] = *(const short8*)(pw3 + (((tn * 8 + s) * 64 + lane) << 3));
        }
        #pragma unroll
        for (int ri = 0; ri < 2; ++ri)
            #pragma unroll
            for (int ci = 0; ci < 2; ++ci)
                acc3[ri][ci] = __builtin_amdgcn_mfma_f32_16x16x32_bf16(
                    a[ri], b[ci], acc3[ri][ci], 0, 0, 0);
    }

    // ---- epilogue 3: +b3, f32 -> out tile in regA ----
    #pragma unroll
    for (int ci = 0; ci < 2; ++ci) {
        int col = w * 32 + ci * 16 + lr;
        float bias = b3v[col];
        #pragma unroll
        for (int ri = 0; ri < 2; ++ri)
            #pragma unroll
            for (int i = 0; i < 4; ++i) {
                int row = ri * 16 + lk * 4 + i;
                float v = acc3[ri][ci][i] + bias;
                *(float*)(regA + SWZ(row, row * 512 + col * 4)) = v;
            }
    }
    __syncthreads();                                   // sync6

    // ---- row-wise L2 normalize + coalesced NT store ----
    #pragma unroll
    for (int pass = 0; pass < 4; ++pass) {
        const int r  = (tid >> 5) + pass * 8;
        const int fl = tid & 31;
        f32x4 v = *(const f32x4*)(regA + SWZ(r, r * 512 + fl * 16));
        float ss = v[0]*v[0] + v[1]*v[1] + v[2]*v[2] + v[3]*v[3];
        ss += __shfl_xor(ss, 1, 32);
        ss += __shfl_xor(ss, 2, 32);
        ss += __shfl_xor(ss, 4, 32);
        ss += __shfl_xor(ss, 8, 32);
        ss += __shfl_xor(ss, 16, 32);
        float inv = 1.f / (sqrtf(ss) + 1e-8f);
        long long row = r0 + r;
        if (row < n_rows) {
            f32x4 o = v * inv;
            __builtin_nontemporal_store(o, (f32x4*)out + row * 32 + fl);
        }
    }
}

// ---------------------------------------------------------------------------
extern "C" void kernel_launch(void* const* d_in, const int* in_sizes, int n_in,
                              void* d_out, int out_size, void* d_ws, size_t ws_size,
                              hipStream_t stream) {
    const float* msg  = (const float*)d_in[0];
    const float* feat = (const float*)d_in[1];
    const float* glob = (const float*)d_in[2];
    const float* W1   = (const float*)d_in[3];
    const float* b1   = (const float*)d_in[4];
    const float* W2   = (const float*)d_in[5];
    const float* b2   = (const float*)d_in[6];
    const float* W3   = (const float*)d_in[7];
    const float* b3   = (const float*)d_in[8];
    float* out = (float*)d_out;

    const int n_rows = in_sizes[1] / 128;   // features is [N,128]

    short* pw1  = (short*)d_ws;             // 98304 bf16
    short* pw2  = pw1 + 98304;              // 65536 bf16
    short* pw3  = pw2 + 65536;              // 32768 bf16
    short* aggb = pw3 + 32768;              // N*128 bf16 (128 MB @ N=500k)

    hipLaunchKernelGGL(prep_weights, dim3(768), dim3(256), 0, stream,
                       W1, W2, W3, pw1, pw2, pw3);

    const int ablocks = (n_rows + 7) / 8;   // 8 rows per block
    hipLaunchKernelGGL(agg_kernel, dim3(ablocks), dim3(256), 0, stream,
                       msg, aggb, n_rows);

    const int nblocks = (n_rows + 31) / 32;
    hipLaunchKernelGGL(node_net, dim3(nblocks), dim3(256), 0, stream,
                       aggb, feat, glob, b1, b2, b3, pw1, pw2, pw3, out, n_rows);
}

// Round 9
// 1080.400 us; speedup vs baseline: 8.9219x; 1.0713x over previous
//
#include <hip/hip_runtime.h>

// ---------------------------------------------------------------------------
// NodeNetwork: agg(sum over deg=16) -> concat(3x128) -> MLP(384-256-256-128)
//              -> row L2 normalize.  N=500000 rows.
// R9: FUSED agg+MLP with NT streams. R8 proved NT keeps weights L2-resident
// (1276->1157). Fusing moves the MLP's L2-weight reads + MFMA under the
// HBM-saturating msg stream (they use different pipes) and kills the 256MB
// aggb round-trip. MLP structure byte-equivalent to R8's node_net.
// ---------------------------------------------------------------------------

typedef short short8   __attribute__((ext_vector_type(8)));
typedef short short4_t __attribute__((ext_vector_type(4)));
typedef float f32x4    __attribute__((ext_vector_type(4)));

#define SWZ(row, off) ((off) ^ (((row) & 7) << 4))

__device__ __forceinline__ unsigned short f2bf(float f) {
    unsigned int u = __float_as_uint(f);
    u += 0x7fffu + ((u >> 16) & 1u);   // round-to-nearest-even
    return (unsigned short)(u >> 16);
}

// ---------------------------------------------------------------------------
// Weight prep (unchanged): fp32->bf16, per-lane MFMA B-fragment order:
//   pw[((tn*KS + ks)*64 + lane)*8 + j] = bf16( W[k][n] )
//   n = tn*16 + (lane&15), k = ks*32 + (lane>>4)*8 + j
// ---------------------------------------------------------------------------
__global__ void prep_weights(const float* __restrict__ W1,
                             const float* __restrict__ W2,
                             const float* __restrict__ W3,
                             short* __restrict__ pw1,
                             short* __restrict__ pw2,
                             short* __restrict__ pw3) {
    int idx = blockIdx.x * 256 + threadIdx.x;
    if (idx < 98304) {                       // W1 [384][256]
        int j = idx & 7, l = (idx >> 3) & 63, g = idx >> 9;
        int ks = g % 12, tn = g / 12;
        int n = tn * 16 + (l & 15);
        int k = ks * 32 + ((l >> 4) << 3) + j;
        pw1[idx] = (short)f2bf(W1[k * 256 + n]);
    } else if (idx < 98304 + 65536) {        // W2 [256][256]
        int e = idx - 98304;
        int j = e & 7, l = (e >> 3) & 63, g = e >> 9;
        int ks = g & 7, tn = g >> 3;
        int n = tn * 16 + (l & 15);
        int k = ks * 32 + ((l >> 4) << 3) + j;
        pw2[e] = (short)f2bf(W2[k * 256 + n]);
    } else if (idx < 98304 + 65536 + 32768) { // W3 [256][128]
        int e = idx - 98304 - 65536;
        int j = e & 7, l = (e >> 3) & 63, g = e >> 9;
        int ks = g & 7, tn = g >> 3;
        int n = tn * 16 + (l & 15);
        int k = ks * 32 + ((l >> 4) << 3) + j;
        pw3[e] = (short)f2bf(W3[k * 128 + n]);
    }
}

// ---------------------------------------------------------------------------
// Fused kernel: 32 rows/block, 256 threads (4 waves), 32KB LDS.
//  Phase A: msg aggregation (NT, 1KB wave-contiguous loads; wave w owns rows
//           [8w,8w+8) as 4 pairs; shfl_xor(32) merge; bf16 -> regB[0:8K]).
//  Phase B: R8's MLP (NT feat/glob at entry, 6 syncs, NT out store).
// ---------------------------------------------------------------------------
__global__ __launch_bounds__(256, 4) void node_net_fused(
    const float* __restrict__ msg,
    const float* __restrict__ feat,
    const float* __restrict__ glob,
    const float* __restrict__ b1v,
    const float* __restrict__ b2v,
    const float* __restrict__ b3v,
    const short* __restrict__ pw1,
    const short* __restrict__ pw2,
    const short* __restrict__ pw3,
    float* __restrict__ out,
    int n_rows)
{
    __shared__ char lds[32768];
    char* regA = lds;            // 16KB
    char* regB = lds + 16384;    // 16KB

    const int tid  = threadIdx.x;
    const int lane = tid & 63;
    const int w    = tid >> 6;
    const int lr   = lane & 15;
    const int lk   = lane >> 4;
    const long long r0 = (long long)blockIdx.x * 32;

    const f32x4 zero4 = {0.f, 0.f, 0.f, 0.f};

    // ---- issue feat/glob NT loads first (consumed after sync1/sync2) ----
    f32x4 fr[4], gr[4];
    #pragma unroll
    for (int q = 0; q < 4; ++q) {
        int r = (tid >> 5) + q * 8;
        long long row = r0 + r;
        fr[q] = zero4; gr[q] = zero4;
        if (row < n_rows) {
            fr[q] = __builtin_nontemporal_load((const f32x4*)feat + row * 32 + (tid & 31));
            gr[q] = __builtin_nontemporal_load((const f32x4*)glob + row * 32 + (tid & 31));
        }
    }

    // ---- Phase A: msg aggregation -> regB[0:8K] ----
    // Wave w owns rows [8w, 8w+8) as 4 pairs; per pair 16 x 1KB NT loads.
    #pragma unroll 1
    for (int pp = 0; pp < 4; ++pp) {
        const int rA = 8 * w + 2 * pp;          // tile-local row (pair base)
        const long long rowA = r0 + rA;
        const f32x4* base = (const f32x4*)msg + rowA * 512;  // 512 f32x4/row
        f32x4 tA[8], tB[8];
        const bool okA = rowA < n_rows;
        const bool okB = (rowA + 1) < n_rows;
        if (okA) {
            #pragma unroll
            for (int i = 0; i < 8; ++i) tA[i] = __builtin_nontemporal_load(base + i * 64 + lane);
        } else {
            #pragma unroll
            for (int i = 0; i < 8; ++i) tA[i] = zero4;
        }
        if (okB) {
            #pragma unroll
            for (int i = 0; i < 8; ++i) tB[i] = __builtin_nontemporal_load(base + 512 + i * 64 + lane);
        } else {
            #pragma unroll
            for (int i = 0; i < 8; ++i) tB[i] = zero4;
        }
        f32x4 sA = ((tA[0] + tA[1]) + (tA[2] + tA[3])) + ((tA[4] + tA[5]) + (tA[6] + tA[7]));
        f32x4 sB = ((tB[0] + tB[1]) + (tB[2] + tB[3])) + ((tB[4] + tB[5]) + (tB[6] + tB[7]));
        #pragma unroll
        for (int c = 0; c < 4; ++c) {
            sA[c] += __shfl_xor(sA[c], 32);
            sB[c] += __shfl_xor(sB[c], 32);
        }
        f32x4 s = (lane < 32) ? sA : sB;
        short4_t s4;
        s4[0] = (short)f2bf(s[0]); s4[1] = (short)f2bf(s[1]);
        s4[2] = (short)f2bf(s[2]); s4[3] = (short)f2bf(s[3]);
        const int orow = rA + (lane >> 5);
        *(short4_t*)(regB + SWZ(orow, orow * 256 + (lane & 31) * 8)) = s4;
    }
    __syncthreads();                                   // sync1

    // ---- stage feat regs -> regA[0:8K] (consumed after sync2) ----
    #pragma unroll
    for (int q = 0; q < 4; ++q) {
        int r = (tid >> 5) + q * 8;
        short4_t s4;
        s4[0] = (short)f2bf(fr[q][0]); s4[1] = (short)f2bf(fr[q][1]);
        s4[2] = (short)f2bf(fr[q][2]); s4[3] = (short)f2bf(fr[q][3]);
        *(short4_t*)(regA + SWZ(r, r * 256 + (tid & 31) * 8)) = s4;
    }

    f32x4 acc1[2][4];
    #pragma unroll
    for (int ri = 0; ri < 2; ++ri)
        #pragma unroll
        for (int ci = 0; ci < 4; ++ci) acc1[ri][ci] = zero4;

    // ---- GEMM1 part 0 (agg), ks = 0..3, reads regB[0:8K] ----
    #pragma unroll
    for (int s = 0; s < 4; ++s) {
        short8 a[2], b[4];
        #pragma unroll
        for (int ri = 0; ri < 2; ++ri) {
            int row = ri * 16 + lr;
            a[ri] = *(const short8*)(regB + SWZ(row, row * 256 + s * 64 + lk * 16));
        }
        #pragma unroll
        for (int ci = 0; ci < 4; ++ci) {
            int tn = w * 4 + ci;
            b[ci] = *(const short8*)(pw1 + (((tn * 12 + s) * 64 + lane) << 3));
        }
        #pragma unroll
        for (int ri = 0; ri < 2; ++ri)
            #pragma unroll
            for (int ci = 0; ci < 4; ++ci)
                acc1[ri][ci] = __builtin_amdgcn_mfma_f32_16x16x32_bf16(
                    a[ri], b[ci], acc1[ri][ci], 0, 0, 0);
    }
    __syncthreads();                                   // sync2

    // ---- stage glob regs -> regB[8K:16K] (consumed after sync3) ----
    #pragma unroll
    for (int q = 0; q < 4; ++q) {
        int r = (tid >> 5) + q * 8;
        short4_t s4;
        s4[0] = (short)f2bf(gr[q][0]); s4[1] = (short)f2bf(gr[q][1]);
        s4[2] = (short)f2bf(gr[q][2]); s4[3] = (short)f2bf(gr[q][3]);
        *(short4_t*)(regB + 8192 + SWZ(r, r * 256 + (tid & 31) * 8)) = s4;
    }

    // ---- GEMM1 part 1 (feat), ks = 4..7, reads regA[0:8K] ----
    #pragma unroll
    for (int s = 0; s < 4; ++s) {
        short8 a[2], b[4];
        #pragma unroll
        for (int ri = 0; ri < 2; ++ri) {
            int row = ri * 16 + lr;
            a[ri] = *(const short8*)(regA + SWZ(row, row * 256 + s * 64 + lk * 16));
        }
        #pragma unroll
        for (int ci = 0; ci < 4; ++ci) {
            int tn = w * 4 + ci;
            b[ci] = *(const short8*)(pw1 + (((tn * 12 + 4 + s) * 64 + lane) << 3));
        }
        #pragma unroll
        for (int ri = 0; ri < 2; ++ri)
            #pragma unroll
            for (int ci = 0; ci < 4; ++ci)
                acc1[ri][ci] = __builtin_amdgcn_mfma_f32_16x16x32_bf16(
                    a[ri], b[ci], acc1[ri][ci], 0, 0, 0);
    }
    __syncthreads();                                   // sync3

    // ---- GEMM1 part 2 (glob), ks = 8..11, reads regB[8K:16K] ----
    #pragma unroll
    for (int s = 0; s < 4; ++s) {
        short8 a[2], b[4];
        #pragma unroll
        for (int ri = 0; ri < 2; ++ri) {
            int row = ri * 16 + lr;
            a[ri] = *(const short8*)(regB + 8192 + SWZ(row, row * 256 + s * 64 + lk * 16));
        }
        #pragma unroll
        for (int ci = 0; ci < 4; ++ci) {
            int tn = w * 4 + ci;
            b[ci] = *(const short8*)(pw1 + (((tn * 12 + 8 + s) * 64 + lane) << 3));
        }
        #pragma unroll
        for (int ri = 0; ri < 2; ++ri)
            #pragma unroll
            for (int ci = 0; ci < 4; ++ci)
                acc1[ri][ci] = __builtin_amdgcn_mfma_f32_16x16x32_bf16(
                    a[ri], b[ci], acc1[ri][ci], 0, 0, 0);
    }

    // ---- epilogue 1: +b1, ReLU, bf16 -> h1 in regA ----
    #pragma unroll
    for (int ci = 0; ci < 4; ++ci) {
        int col = w * 64 + ci * 16 + lr;
        float bias = b1v[col];
        #pragma unroll
        for (int ri = 0; ri < 2; ++ri)
            #pragma unroll
            for (int i = 0; i < 4; ++i) {
                int row = ri * 16 + lk * 4 + i;
                float v = fmaxf(acc1[ri][ci][i] + bias, 0.f);
                *(short*)(regA + SWZ(row, row * 512 + col * 2)) = (short)f2bf(v);
            }
    }
    __syncthreads();                                   // sync4

    // ---- GEMM2: h1 @ W2 (reads regA) ----
    f32x4 acc2[2][4];
    #pragma unroll
    for (int ri = 0; ri < 2; ++ri)
        #pragma unroll
        for (int ci = 0; ci < 4; ++ci) acc2[ri][ci] = zero4;

    #pragma unroll
    for (int s = 0; s < 8; ++s) {
        short8 a[2], b[4];
        #pragma unroll
        for (int ri = 0; ri < 2; ++ri) {
            int row = ri * 16 + lr;
            a[ri] = *(const short8*)(regA + SWZ(row, row * 512 + s * 64 + lk * 16));
        }
        #pragma unroll
        for (int ci = 0; ci < 4; ++ci) {
            int tn = w * 4 + ci;
            b[ci] = *(const short8*)(pw2 + (((tn * 8 + s) * 64 + lane) << 3));
        }
        #pragma unroll
        for (int ri = 0; ri < 2; ++ri)
            #pragma unroll
            for (int ci = 0; ci < 4; ++ci)
                acc2[ri][ci] = __builtin_amdgcn_mfma_f32_16x16x32_bf16(
                    a[ri], b[ci], acc2[ri][ci], 0, 0, 0);
    }

    // ---- epilogue 2: +b2, ReLU, bf16 -> h2 in regB ----
    #pragma unroll
    for (int ci = 0; ci < 4; ++ci) {
        int col = w * 64 + ci * 16 + lr;
        float bias = b2v[col];
        #pragma unroll
        for (int ri = 0; ri < 2; ++ri)
            #pragma unroll
            for (int i = 0; i < 4; ++i) {
                int row = ri * 16 + lk * 4 + i;
                float v = fmaxf(acc2[ri][ci][i] + bias, 0.f);
                *(short*)(regB + SWZ(row, row * 512 + col * 2)) = (short)f2bf(v);
            }
    }
    __syncthreads();                                   // sync5

    // ---- GEMM3: h2 @ W3 (reads regB) ----
    f32x4 acc3[2][2];
    #pragma unroll
    for (int ri = 0; ri < 2; ++ri)
        #pragma unroll
        for (int ci = 0; ci < 2; ++ci) acc3[ri][ci] = zero4;

    #pragma unroll
    for (int s = 0; s < 8; ++s) {
        short8 a[2], b[2];
        #pragma unroll
        for (int ri = 0; ri < 2; ++ri) {
            int row = ri * 16 + lr;
            a[ri] = *(const short8*)(regB + SWZ(row, row * 512 + s * 64 + lk * 16));
        }
        #pragma unroll
        for (int ci = 0; ci < 2; ++ci) {
            int tn = w * 2 + ci;
            b[ci] = *(const short8*)(pw3 + (((tn * 8 + s) * 64 + lane) << 3));
        }
        #pragma unroll
        for (int ri = 0; ri < 2; ++ri)
            #pragma unroll
            for (int ci = 0; ci < 2; ++ci)
                acc3[ri][ci] = __builtin_amdgcn_mfma_f32_16x16x32_bf16(
                    a[ri], b[ci], acc3[ri][ci], 0, 0, 0);
    }

    // ---- epilogue 3: +b3, f32 -> out tile in regA ----
    #pragma unroll
    for (int ci = 0; ci < 2; ++ci) {
        int col = w * 32 + ci * 16 + lr;
        float bias = b3v[col];
        #pragma unroll
        for (int ri = 0; ri < 2; ++ri)
            #pragma unroll
            for (int i = 0; i < 4; ++i) {
                int row = ri * 16 + lk * 4 + i;
                float v = acc3[ri][ci][i] + bias;
                *(float*)(regA + SWZ(row, row * 512 + col * 4)) = v;
            }
    }
    __syncthreads();                                   // sync6

    // ---- row-wise L2 normalize + coalesced NT store ----
    #pragma unroll
    for (int pass = 0; pass < 4; ++pass) {
        const int r  = (tid >> 5) + pass * 8;
        const int fl = tid & 31;
        f32x4 v = *(const f32x4*)(regA + SWZ(r, r * 512 + fl * 16));
        float ss = v[0]*v[0] + v[1]*v[1] + v[2]*v[2] + v[3]*v[3];
        ss += __shfl_xor(ss, 1, 32);
        ss += __shfl_xor(ss, 2, 32);
        ss += __shfl_xor(ss, 4, 32);
        ss += __shfl_xor(ss, 8, 32);
        ss += __shfl_xor(ss, 16, 32);
        float inv = 1.f / (sqrtf(ss) + 1e-8f);
        long long row = r0 + r;
        if (row < n_rows) {
            f32x4 o = v * inv;
            __builtin_nontemporal_store(o, (f32x4*)out + row * 32 + fl);
        }
    }
}

// ---------------------------------------------------------------------------
extern "C" void kernel_launch(void* const* d_in, const int* in_sizes, int n_in,
                              void* d_out, int out_size, void* d_ws, size_t ws_size,
                              hipStream_t stream) {
    const float* msg  = (const float*)d_in[0];
    const float* feat = (const float*)d_in[1];
    const float* glob = (const float*)d_in[2];
    const float* W1   = (const float*)d_in[3];
    const float* b1   = (const float*)d_in[4];
    const float* W2   = (const float*)d_in[5];
    const float* b2   = (const float*)d_in[6];
    const float* W3   = (const float*)d_in[7];
    const float* b3   = (const float*)d_in[8];
    float* out = (float*)d_out;

    const int n_rows = in_sizes[1] / 128;   // features is [N,128]

    short* pw1 = (short*)d_ws;              // 98304 bf16
    short* pw2 = pw1 + 98304;               // 65536 bf16
    short* pw3 = pw2 + 65536;               // 32768 bf16

    hipLaunchKernelGGL(prep_weights, dim3(768), dim3(256), 0, stream,
                       W1, W2, W3, pw1, pw2, pw3);

    const int nblocks = (n_rows + 31) / 32;
    hipLaunchKernelGGL(node_net_fused, dim3(nblocks), dim3(256), 0, stream,
                       msg, feat, glob, b1, b2, b3, pw1, pw2, pw3, out, n_rows);
}